// Round 1
// baseline (105.166 us; speedup 1.0000x reference)
//
#include <hip/hip_runtime.h>

// Propagation: out[b, d*3+o, h, w] = x[b, d, h, w+o-1]  (zero-padded along W)
// for each of the two input tensors (offset_x -> first half of d_out,
// offset_y -> second half). Pure memory-bound shift/copy.

#define BB 2
#define DD 16
#define HH 512
#define WW 960
#define W4 (WW / 4)          // 240 float4 per row
#define FF 3

__global__ __launch_bounds__(256) void propagate_kernel(
    const float* __restrict__ x,
    const float* __restrict__ y,
    float* __restrict__ out)
{
    const int perTensor = BB * DD * HH * W4;          // 3,932,160
    const int total     = 2 * perTensor;              // 7,864,320
    const int outPerTensor = BB * DD * FF * HH * WW;  // 47,185,920

    for (int idx = blockIdx.x * blockDim.x + threadIdx.x;
         idx < total;
         idx += gridDim.x * blockDim.x)
    {
        int i = idx;
        const float* src;
        float* dst;
        if (i < perTensor) {
            src = x;  dst = out;
        } else {
            src = y;  dst = out + outPerTensor;  i -= perTensor;
        }

        const int w4 = i % W4;
        int t = i / W4;
        const int h = t % HH;
        t /= HH;
        const int d = t % DD;
        const int b = t / DD;
        const int w = w4 * 4;

        const float* in_row = src + ((b * DD + d) * HH + h) * WW;

        const float4 v = *reinterpret_cast<const float4*>(in_row + w);
        const float left  = (w == 0)       ? 0.0f : in_row[w - 1];
        const float right = (w + 4 == WW)  ? 0.0f : in_row[w + 4];

        // output channel base: c = d*3 + o; layout [B, D*3, H, W]
        float* out_base = dst + (((b * (DD * FF) + d * FF) * HH + h) * WW) + w;
        const int plane = HH * WW;  // stride between consecutive o channels

        // o = 0: source w-1 .. w+2
        *reinterpret_cast<float4*>(out_base) =
            make_float4(left, v.x, v.y, v.z);
        // o = 1: source w .. w+3 (identity)
        *reinterpret_cast<float4*>(out_base + plane) = v;
        // o = 2: source w+1 .. w+4
        *reinterpret_cast<float4*>(out_base + 2 * plane) =
            make_float4(v.y, v.z, v.w, right);
    }
}

extern "C" void kernel_launch(void* const* d_in, const int* in_sizes, int n_in,
                              void* d_out, int out_size, void* d_ws, size_t ws_size,
                              hipStream_t stream)
{
    const float* x = (const float*)d_in[0];
    const float* y = (const float*)d_in[1];
    float* out = (float*)d_out;

    const int total = 2 * BB * DD * HH * W4;  // 7,864,320 float4-work items
    int blocks = (total + 255) / 256;
    if (blocks > 2048) blocks = 2048;         // grid-stride, ~8 blocks/CU

    propagate_kernel<<<blocks, 256, 0, stream>>>(x, y, out);
}

// Round 3
// 76.885 us; speedup vs baseline: 1.3678x; 1.3678x over previous
//
#include <hip/hip_runtime.h>

// Propagation: out[b, d*3+o, h, w] = x[b, d, h, w+o-1]  (zero-padded along W)
// offset_x -> first half of d_out, offset_y -> second half.
// Pure memory-bound shift/copy: 126 MB read + 377 MB write.

#define BB 2
#define DD 16
#define HH 512
#define WW 960
#define W4 (WW / 4)          // 240 float4 per row
#define FF 3

typedef float f32x4 __attribute__((ext_vector_type(4)));  // native vector: OK for nontemporal builtins

__global__ __launch_bounds__(256) void propagate_kernel(
    const float* __restrict__ x,
    const float* __restrict__ y,
    float* __restrict__ out)
{
    const int perTensor = BB * DD * HH * W4;          // 3,932,160
    const int outPerTensor = BB * DD * FF * HH * WW;  // 47,185,920

    int i = blockIdx.x * blockDim.x + threadIdx.x;    // one float4 per thread

    const float* src;
    float* dst;
    if (i < perTensor) {
        src = x;  dst = out;
    } else {
        src = y;  dst = out + outPerTensor;  i -= perTensor;
    }

    const int w4 = i % W4;
    int t = i / W4;
    const int h = t % HH;
    t /= HH;
    const int d = t % DD;
    const int b = t / DD;
    const int w = w4 * 4;

    const float* in_row = src + ((b * DD + d) * HH + h) * WW;

    const f32x4 v = *reinterpret_cast<const f32x4*>(in_row + w);
    const float left  = (w == 0)       ? 0.0f : in_row[w - 1];
    const float right = (w + 4 == WW)  ? 0.0f : in_row[w + 4];

    // output channel base: c = d*3 + o; layout [B, D*3, H, W]
    float* out_base = dst + (((b * (DD * FF) + d * FF) * HH + h) * WW) + w;
    const int plane = HH * WW;  // stride between consecutive o channels

    const f32x4 s0 = {left, v.x, v.y, v.z};
    const f32x4 s2 = {v.y, v.z, v.w, right};

    // Non-temporal: output is write-once, never re-read -> don't pollute L2.
    __builtin_nontemporal_store(s0, reinterpret_cast<f32x4*>(out_base));
    __builtin_nontemporal_store(v,  reinterpret_cast<f32x4*>(out_base + plane));
    __builtin_nontemporal_store(s2, reinterpret_cast<f32x4*>(out_base + 2 * plane));
}

extern "C" void kernel_launch(void* const* d_in, const int* in_sizes, int n_in,
                              void* d_out, int out_size, void* d_ws, size_t ws_size,
                              hipStream_t stream)
{
    const float* x = (const float*)d_in[0];
    const float* y = (const float*)d_in[1];
    float* out = (float*)d_out;

    const int total = 2 * BB * DD * HH * W4;  // 7,864,320 float4-work items
    const int blocks = total / 256;           // 30,720 — exact, no tail

    propagate_kernel<<<blocks, 256, 0, stream>>>(x, y, out);
}